// Round 9
// baseline (792.073 us; speedup 1.0000x reference)
//
#include <hip/hip_runtime.h>
#include <math.h>

// Problem constants (match reference setup_inputs)
constexpr int NA = 4096, NP = 100000, E_AP = 500000, E_PA = 500000;
constexpr int D = 128, DFF = 2048, NOUT = 16, IN_A = 128, IN_P = 256;

typedef __attribute__((ext_vector_type(8))) short bf16x8;
typedef __attribute__((ext_vector_type(4))) float f32x4;
typedef unsigned int u32;

// round-to-nearest-even f32 -> bf16 bits
__device__ __forceinline__ ushort f2b(float x) {
    union { float f; unsigned u; } v; v.f = x;
    unsigned r = v.u + 0x7fff + ((v.u >> 16) & 1);
    return (ushort)(r >> 16);
}
__device__ __forceinline__ float b2f(ushort h) {
    union { unsigned u; float f; } v; v.u = (unsigned)h << 16;
    return v.f;
}
__device__ __forceinline__ u32 fbits(float x) {
    union { float f; u32 u; } v; v.f = x; return v.u;
}

// ---------------------------------------------------------------------------
// Streaming GEMM for N==128, K<=256 (B fits in LDS whole).
// B [128, ldb] bf16 staged ONCE into fragment-ordered LDS; then each wave
// independently processes 16-row stripes of A with NO inner barriers:
//   per k-chunk: 1 global A-load (fp32->bf16 in-register if Af32) +
//   8 ds_read_b128 + 8 MFMA. Pure pipelined stream -> HBM-BW-bound.
// Dynamic LDS: (K/32)*8*1024 bytes.
__global__ __launch_bounds__(256) void gemm_stream(
    const ushort* __restrict__ Abf, const float* __restrict__ Af32, int lda,
    const ushort* __restrict__ B, int ldb,
    const float* __restrict__ bias,
    float* __restrict__ outf, ushort* __restrict__ outh, int ldc,
    int M, int K, int act)
{
    extern __shared__ ushort sB[];
    const int wave = threadIdx.x >> 6;
    const int lane = threadIdx.x & 63;
    const int l16 = lane & 15, quad = lane >> 4;
    const int sc = lane >> 4, sr = lane & 15;
    const int nkc = K >> 5;

    // stage B: block (g,c) = 1KB in fragment order, one wave-op per block
    for (int b = wave; b < 8 * nkc; b += 4) {
        int g = b / nkc, c = b - g * nkc;
        const ushort* gp = B + (long)(g * 16 + sr) * ldb + c * 32 + sc * 8;
        *(bf16x8*)(sB + b * 512 + lane * 8) = *(const bf16x8*)gp;
    }
    __syncthreads();

    const int nstripes = (M + 15) >> 4;
    for (int s = blockIdx.x * 4 + wave; s < nstripes; s += gridDim.x * 4) {
        int row0 = s * 16;
        f32x4 acc[8] = {};
        #pragma unroll 4
        for (int c = 0; c < nkc; ++c) {
            int ar = min(row0 + l16, M - 1);
            bf16x8 af;
            if (Af32) {
                const float* gp = Af32 + (long)ar * lda + c * 32 + quad * 8;
                float4 f0 = *(const float4*)gp;
                float4 f1 = *(const float4*)(gp + 4);
                af[0] = (short)f2b(f0.x); af[1] = (short)f2b(f0.y);
                af[2] = (short)f2b(f0.z); af[3] = (short)f2b(f0.w);
                af[4] = (short)f2b(f1.x); af[5] = (short)f2b(f1.y);
                af[6] = (short)f2b(f1.z); af[7] = (short)f2b(f1.w);
            } else {
                af = *(const bf16x8*)(Abf + (long)ar * lda + c * 32 + quad * 8);
            }
            #pragma unroll
            for (int g = 0; g < 8; ++g) {
                bf16x8 bf = *(const bf16x8*)(sB + (g * nkc + c) * 512 + lane * 8);
                acc[g] = __builtin_amdgcn_mfma_f32_16x16x32_bf16(af, bf, acc[g], 0, 0, 0);
            }
        }
        #pragma unroll
        for (int g = 0; g < 8; ++g) {
            #pragma unroll
            for (int r = 0; r < 4; ++r) {
                int row = row0 + quad * 4 + r;
                if (row >= M) continue;
                int col = g * 16 + l16;
                float v = acc[g][r] + (bias ? bias[col] : 0.f);
                if (act) v = fmaxf(v, 0.f);
                if (outf) outf[(long)row * ldc + col] = v;
                if (outh) outh[(long)row * ldc + col] = f2b(v);
            }
        }
    }
}

// ---------------------------------------------------------------------------
// Tiled bf16 MFMA GEMM (kept for FFN where B doesn't fit LDS).
// gridDim.z > 1: split-K with fp32 atomicAdd (outf pre-zeroed, bias folded
// downstream).
__global__ __launch_bounds__(256) void gemm_bf16(
    const ushort* __restrict__ Abf, const float* __restrict__ Af32, int lda,
    const ushort* __restrict__ B, int ldb,
    const float* __restrict__ bias,
    float* __restrict__ outf, ushort* __restrict__ outh, int ldc,
    int M, int N, int K, int act)
{
    __shared__ ushort sA[128 * 32];
    __shared__ ushort sB2[128 * 32];
    const int wave = threadIdx.x >> 6;
    const int lane = threadIdx.x & 63;
    const int l16 = lane & 15, quad = lane >> 4;
    const int row0 = blockIdx.y * 128;
    const int col0 = blockIdx.x * 128;
    const int wr0 = (wave >> 1) * 64, wc0 = (wave & 1) * 64;
    const int nz = gridDim.z;
    const int ksub = K / nz;
    const int kbeg = blockIdx.z * ksub, kend = kbeg + ksub;

    f32x4 acc[4][4] = {};

    const int sc = lane >> 4, sr = lane & 15;

    for (int k0 = kbeg; k0 < kend; k0 += 32) {
        if (k0 != kbeg) __syncthreads();
        #pragma unroll
        for (int t = 0; t < 2; ++t) {
            int g = wave * 2 + t;
            int ar = min(row0 + g * 16 + sr, M - 1);
            if (Af32) {
                const float* gp = Af32 + (long)ar * lda + k0 + sc * 8;
                float4 f0 = *(const float4*)gp;
                float4 f1 = *(const float4*)(gp + 4);
                bf16x8 hv;
                hv[0] = (short)f2b(f0.x); hv[1] = (short)f2b(f0.y);
                hv[2] = (short)f2b(f0.z); hv[3] = (short)f2b(f0.w);
                hv[4] = (short)f2b(f1.x); hv[5] = (short)f2b(f1.y);
                hv[6] = (short)f2b(f1.z); hv[7] = (short)f2b(f1.w);
                *(bf16x8*)(sA + g * 512 + lane * 8) = hv;
            } else {
                const ushort* gpa = Abf + (long)ar * lda + k0 + sc * 8;
                __builtin_amdgcn_global_load_lds(
                    (const __attribute__((address_space(1))) u32*)gpa,
                    (__attribute__((address_space(3))) u32*)(sA + g * 512), 16, 0, 0);
            }
            int br = col0 + g * 16 + sr;
            const ushort* gpb = B + (long)br * ldb + k0 + sc * 8;
            __builtin_amdgcn_global_load_lds(
                (const __attribute__((address_space(1))) u32*)gpb,
                (__attribute__((address_space(3))) u32*)(sB2 + g * 512), 16, 0, 0);
        }
        __syncthreads();

        bf16x8 af[4], bf[4];
        #pragma unroll
        for (int i = 0; i < 4; ++i)
            af[i] = *(const bf16x8*)(sA + ((wr0 >> 4) + i) * 512 + lane * 8);
        #pragma unroll
        for (int j = 0; j < 4; ++j)
            bf[j] = *(const bf16x8*)(sB2 + ((wc0 >> 4) + j) * 512 + lane * 8);
        #pragma unroll
        for (int i = 0; i < 4; ++i)
            #pragma unroll
            for (int j = 0; j < 4; ++j)
                acc[i][j] = __builtin_amdgcn_mfma_f32_16x16x32_bf16(
                    af[i], bf[j], acc[i][j], 0, 0, 0);
    }

    #pragma unroll
    for (int i = 0; i < 4; ++i) {
        #pragma unroll
        for (int r = 0; r < 4; ++r) {
            int row = row0 + wr0 + i * 16 + quad * 4 + r;
            if (row >= M) continue;
            #pragma unroll
            for (int j = 0; j < 4; ++j) {
                int col = col0 + wc0 + j * 16 + l16;
                if (nz > 1) {
                    atomicAdd(&outf[(long)row * ldc + col], acc[i][j][r]);
                } else {
                    float v = acc[i][j][r] + (bias ? bias[col] : 0.f);
                    if (act) v = fmaxf(v, 0.f);
                    if (outf) outf[(long)row * ldc + col] = v;
                    if (outh) outh[(long)row * ldc + col] = f2b(v);
                }
            }
        }
    }
}

// ---------------------------------------------------------------------------
// Wf_l = Wo_l @ Wv_l (bf16 out),  beff_l = bo_l + Wo_l @ bv_l (fp32)
__global__ __launch_bounds__(256) void fuse_weights(
    const float* __restrict__ Wv0, const float* __restrict__ bv0,
    const float* __restrict__ Wo0, const float* __restrict__ bo0,
    const float* __restrict__ Wv1, const float* __restrict__ bv1,
    const float* __restrict__ Wo1, const float* __restrict__ bo1,
    const float* __restrict__ Wv2, const float* __restrict__ bv2,
    const float* __restrict__ Wo2, const float* __restrict__ bo2,
    ushort* __restrict__ Wfb, float* __restrict__ beff)
{
    int blk = blockIdx.x;
    if (blk >= 192) {
        int l = blk - 192;
        const float* bv = l == 0 ? bv0 : (l == 1 ? bv1 : bv2);
        const float* Wo = l == 0 ? Wo0 : (l == 1 ? Wo1 : Wo2);
        const float* bo = l == 0 ? bo0 : (l == 1 ? bo1 : bo2);
        if (threadIdx.x < 128) {
            int r = threadIdx.x;
            float acc = bo[r];
            #pragma unroll 8
            for (int j = 0; j < 128; ++j) acc += Wo[r * 128 + j] * bv[j];
            beff[l * 128 + r] = acc;
        }
        return;
    }
    int l = blk >> 6;
    const float* Wv = l == 0 ? Wv0 : (l == 1 ? Wv1 : Wv2);
    const float* Wo = l == 0 ? Wo0 : (l == 1 ? Wo1 : Wo2);
    int r = (blk & 63) * 2 + (threadIdx.x >> 7);
    int c = threadIdx.x & 127;
    float acc = 0.f;
    #pragma unroll 8
    for (int j = 0; j < 128; ++j)
        acc += Wo[r * 128 + j] * Wv[j * 128 + c];
    Wfb[l * 16384 + r * 128 + c] = f2b(acc);
}

// ---------------------------------------------------------------------------
// CSR build: histogram, hierarchical exclusive scan, cursor copy, slot fill
__global__ void hist_kernel(const int* __restrict__ dst, int* __restrict__ cnt, int E)
{
    int e = blockIdx.x * 256 + threadIdx.x;
    if (e < E) atomicAdd(&cnt[dst[e]], 1);
}

__global__ __launch_bounds__(256) void scan_local(
    const int* __restrict__ in, int* __restrict__ out,
    int* __restrict__ bsum, int n)
{
    __shared__ int wsum[4];
    int t = threadIdx.x;
    int base = blockIdx.x * 1024 + t * 4;
    int v0 = (base + 0 < n) ? in[base + 0] : 0;
    int v1 = (base + 1 < n) ? in[base + 1] : 0;
    int v2 = (base + 2 < n) ? in[base + 2] : 0;
    int v3 = (base + 3 < n) ? in[base + 3] : 0;
    int tsum = v0 + v1 + v2 + v3;
    int lane = t & 63;
    int x = tsum;
    #pragma unroll
    for (int o = 1; o < 64; o <<= 1) {
        int y = __shfl_up(x, o, 64);
        if (lane >= o) x += y;
    }
    int wid = t >> 6;
    if (lane == 63) wsum[wid] = x;
    __syncthreads();
    int woff = 0;
    #pragma unroll
    for (int ww = 0; ww < 3; ++ww) if (ww < wid) woff += wsum[ww];
    int excl = x - tsum + woff;
    if (base + 0 < n) out[base + 0] = excl;
    if (base + 1 < n) out[base + 1] = excl + v0;
    if (base + 2 < n) out[base + 2] = excl + v0 + v1;
    if (base + 3 < n) out[base + 3] = excl + v0 + v1 + v2;
    if (bsum && t == 255) bsum[blockIdx.x] = excl + tsum;
}

__global__ void scan_add(int* __restrict__ off, const int* __restrict__ bofs, int n)
{
    int i = blockIdx.x * 256 + threadIdx.x;
    if (i < n) off[i] += bofs[i >> 10];
}

__global__ void copy_int_kernel(const int* __restrict__ a, int* __restrict__ b, int n)
{
    int i = blockIdx.x * 256 + threadIdx.x;
    if (i < n) b[i] = a[i];
}

__global__ void fill_csr_kernel(const int* __restrict__ src, const int* __restrict__ dst,
                                int* __restrict__ cur, int* __restrict__ esrc, int E)
{
    int e = blockIdx.x * 256 + threadIdx.x;
    if (e >= E) return;
    int slot = atomicAdd(&cur[dst[e]], 1);
    esrc[slot] = src[e];
}

// ---------------------------------------------------------------------------
// gather + mean only (bf16 in -> bf16 out). One 32-lane group per dst row.
__global__ __launch_bounds__(256) void gather_mean(
    const ushort* __restrict__ z, const int* __restrict__ off,
    const int* __restrict__ cnt, const int* __restrict__ esrc,
    ushort* __restrict__ outh, int R)
{
    int grp = threadIdx.x >> 5;
    int tg  = threadIdx.x & 31;
    int row = blockIdx.x * 8 + grp;
    if (row >= R) return;
    int e0 = off[row], deg = cnt[row];
    int eend = e0 + deg;
    float a0 = 0.f, a1 = 0.f, a2 = 0.f, a3 = 0.f;
    int e = e0;
    for (; e + 4 <= eend; e += 4) {
        int s0 = esrc[e], s1 = esrc[e + 1], s2 = esrc[e + 2], s3 = esrc[e + 3];
        ushort4 v0 = ((const ushort4*)(z + (long)s0 * 128))[tg];
        ushort4 v1 = ((const ushort4*)(z + (long)s1 * 128))[tg];
        ushort4 v2 = ((const ushort4*)(z + (long)s2 * 128))[tg];
        ushort4 v3 = ((const ushort4*)(z + (long)s3 * 128))[tg];
        a0 += b2f(v0.x) + b2f(v1.x) + b2f(v2.x) + b2f(v3.x);
        a1 += b2f(v0.y) + b2f(v1.y) + b2f(v2.y) + b2f(v3.y);
        a2 += b2f(v0.z) + b2f(v1.z) + b2f(v2.z) + b2f(v3.z);
        a3 += b2f(v0.w) + b2f(v1.w) + b2f(v2.w) + b2f(v3.w);
    }
    for (; e < eend; ++e) {
        int s = esrc[e];
        ushort4 v = ((const ushort4*)(z + (long)s * 128))[tg];
        a0 += b2f(v.x); a1 += b2f(v.y); a2 += b2f(v.z); a3 += b2f(v.w);
    }
    float inv = 1.f / fmaxf((float)deg, 1.f);
    ushort4 h4 = {f2b(a0 * inv), f2b(a1 * inv), f2b(a2 * inv), f2b(a3 * inv)};
    ((ushort4*)(outh + (long)row * 128))[tg] = h4;
}

// ---------------------------------------------------------------------------
// Fused gather(bf16) + mean + residual(bf16) + LayerNorm -> bf16 out.
__global__ __launch_bounds__(256) void gather_mean_ln(
    const ushort* __restrict__ z, const int* __restrict__ off,
    const int* __restrict__ cnt, const int* __restrict__ esrc,
    const ushort* __restrict__ base, const float* __restrict__ g,
    const float* __restrict__ b, ushort* __restrict__ outh, int R)
{
    int grp = threadIdx.x >> 5;
    int tg  = threadIdx.x & 31;
    int row = blockIdx.x * 8 + grp;
    if (row >= R) return;
    int e0 = off[row], deg = cnt[row];
    int eend = e0 + deg;
    float a0 = 0.f, a1 = 0.f, a2 = 0.f, a3 = 0.f;
    int e = e0;
    for (; e + 4 <= eend; e += 4) {
        int s0 = esrc[e], s1 = esrc[e + 1], s2 = esrc[e + 2], s3 = esrc[e + 3];
        ushort4 v0 = ((const ushort4*)(z + (long)s0 * 128))[tg];
        ushort4 v1 = ((const ushort4*)(z + (long)s1 * 128))[tg];
        ushort4 v2 = ((const ushort4*)(z + (long)s2 * 128))[tg];
        ushort4 v3 = ((const ushort4*)(z + (long)s3 * 128))[tg];
        a0 += b2f(v0.x) + b2f(v1.x) + b2f(v2.x) + b2f(v3.x);
        a1 += b2f(v0.y) + b2f(v1.y) + b2f(v2.y) + b2f(v3.y);
        a2 += b2f(v0.z) + b2f(v1.z) + b2f(v2.z) + b2f(v3.z);
        a3 += b2f(v0.w) + b2f(v1.w) + b2f(v2.w) + b2f(v3.w);
    }
    for (; e < eend; ++e) {
        int s = esrc[e];
        ushort4 v = ((const ushort4*)(z + (long)s * 128))[tg];
        a0 += b2f(v.x); a1 += b2f(v.y); a2 += b2f(v.z); a3 += b2f(v.w);
    }
    float inv = 1.f / fmaxf((float)deg, 1.f);
    ushort4 bs = ((const ushort4*)(base + (long)row * 128))[tg];
    float x0 = a0 * inv + b2f(bs.x), x1 = a1 * inv + b2f(bs.y);
    float x2 = a2 * inv + b2f(bs.z), x3 = a3 * inv + b2f(bs.w);
    float s1 = x0 + x1 + x2 + x3;
    #pragma unroll
    for (int o = 1; o < 32; o <<= 1) s1 += __shfl_xor(s1, o, 64);
    float mu = s1 * (1.f / 128.f);
    float d0 = x0 - mu, d1 = x1 - mu, d2 = x2 - mu, d3 = x3 - mu;
    float s2 = d0 * d0 + d1 * d1 + d2 * d2 + d3 * d3;
    #pragma unroll
    for (int o = 1; o < 32; o <<= 1) s2 += __shfl_xor(s2, o, 64);
    float rstd = rsqrtf(s2 * (1.f / 128.f) + 1e-5f);
    float4 gv = ((const float4*)g)[tg];
    float4 bv = ((const float4*)b)[tg];
    ushort4 h4;
    h4.x = f2b(d0 * rstd * gv.x + bv.x);
    h4.y = f2b(d1 * rstd * gv.y + bv.y);
    h4.z = f2b(d2 * rstd * gv.z + bv.z);
    h4.w = f2b(d3 * rstd * gv.w + bv.w);
    ((ushort4*)(outh + (long)row * 128))[tg] = h4;
}

// ---------------------------------------------------------------------------
// out = LN(a + bias + base)*g + b ; dual fp32/bf16 stores, out leading dim.
__global__ __launch_bounds__(128) void mean_add_ln(
    const float* __restrict__ a, const float* __restrict__ bias,
    const float* __restrict__ basef, const ushort* __restrict__ baseh,
    const float* __restrict__ g, const float* __restrict__ b,
    float* __restrict__ outf, ushort* __restrict__ outh, int out_ld, int R)
{
    int row = blockIdx.x;
    if (row >= R) return;
    int d = threadIdx.x;
    float x = a[(long)row * 128 + d];
    if (bias) x += bias[d];
    if (basef) x += basef[(long)row * 128 + d];
    if (baseh) x += b2f(baseh[(long)row * 128 + d]);

    __shared__ float red[4];
    float s = x;
    #pragma unroll
    for (int o = 32; o >= 1; o >>= 1) s += __shfl_xor(s, o, 64);
    if ((d & 63) == 0) red[d >> 6] = s;
    __syncthreads();
    float mu = (red[0] + red[1]) * (1.f / 128.f);
    float dx = x - mu;
    float s2 = dx * dx;
    #pragma unroll
    for (int o = 32; o >= 1; o >>= 1) s2 += __shfl_xor(s2, o, 64);
    if ((d & 63) == 0) red[2 + (d >> 6)] = s2;
    __syncthreads();
    float var = (red[2] + red[3]) * (1.f / 128.f);
    float v = dx * rsqrtf(var + 1e-5f) * g[d] + b[d];
    if (outf) outf[(long)row * out_ld + d] = v;
    if (outh) outh[(long)row * out_ld + d] = f2b(v);
}

// ---------------------------------------------------------------------------
struct CvtArgs { const float* in[6]; ushort* out[6]; int n4[6]; };
__global__ void cvt_multi(CvtArgs a)
{
    int j = blockIdx.y;
    int i = blockIdx.x * 256 + threadIdx.x;
    if (i >= a.n4[j]) return;
    float4 v = ((const float4*)a.in[j])[i];
    ushort4 o;
    o.x = f2b(v.x); o.y = f2b(v.y); o.z = f2b(v.z); o.w = f2b(v.w);
    ((ushort4*)a.out[j])[i] = o;
}

// ---------------------------------------------------------------------------
// Flash attention (split-K). Partials combine linearly (no max-subtraction).
__global__ __launch_bounds__(256) void flash_attn(
    const ushort* __restrict__ qkvb,
    float* __restrict__ opart, float* __restrict__ lpart_g)
{
    const int qt = blockIdx.x;
    const int mh = blockIdx.y;
    const int ks = blockIdx.z;
    const int m = mh >> 2, h = mh & 3;
    const int wave = threadIdx.x >> 6;
    const int lane = threadIdx.x & 63;
    const int l16 = lane & 15, quad = lane >> 4;

    __shared__ ushort sK[64 * 40];
    __shared__ ushort sV[32 * 72];
    __shared__ ushort sP[4][16 * 72];

    const int q0 = qt * 64 + wave * 16;
    const float qs = 0.17677669529663687f * 1.4426950408889634f;
    bf16x8 qf;
    {
        bf16x8 qraw = *(const bf16x8*)(qkvb + ((long)(q0 + l16) * 2 + m) * 384 + h * 32 + quad * 8);
        #pragma unroll
        for (int j = 0; j < 8; ++j)
            qf[j] = (short)f2b(b2f((ushort)qraw[j]) * qs);
    }

    f32x4 oacc0 = {0.f, 0.f, 0.f, 0.f};
    f32x4 oacc1 = {0.f, 0.f, 0.f, 0.f};
    float lp = 0.f;

    const int kbeg = ks * (NA / 4);
    for (int kt = 0; kt < NA / 4; kt += 64) {
        int k0 = kbeg + kt;
        __syncthreads();
        {
            int key = threadIdx.x >> 2, seg = threadIdx.x & 3;
            bf16x8 kv = *(const bf16x8*)(qkvb + ((long)(k0 + key) * 2 + m) * 384 + 128 + h * 32 + seg * 8);
            *(bf16x8*)(sK + key * 40 + seg * 8) = kv;
        }
        {
            int kp = threadIdx.x & 31, dc = (threadIdx.x >> 5) * 4;
            const ushort* vp = qkvb + ((long)(k0 + kp * 2) * 2 + m) * 384 + 256 + h * 32 + dc;
            ushort4 v0 = *(const ushort4*)vp;
            ushort4 v1 = *(const ushort4*)(vp + 768);
            u32* sv32 = (u32*)sV;
            sv32[(dc + 0) * 36 + kp] = (u32)v0.x | ((u32)v1.x << 16);
            sv32[(dc + 1) * 36 + kp] = (u32)v0.y | ((u32)v1.y << 16);
            sv32[(dc + 2) * 36 + kp] = (u32)v0.z | ((u32)v1.z << 16);
            sv32[(dc + 3) * 36 + kp] = (u32)v0.w | ((u32)v1.w << 16);
        }
        __syncthreads();

        #pragma unroll
        for (int t = 0; t < 4; ++t) {
            bf16x8 kf = *(const bf16x8*)(sK + (t * 16 + l16) * 40 + quad * 8);
            f32x4 s = {0.f, 0.f, 0.f, 0.f};
            s = __builtin_amdgcn_mfma_f32_16x16x32_bf16(kf, qf, s, 0, 0, 0);
            float p0 = exp2f(s[0]), p1 = exp2f(s[1]);
            float p2 = exp2f(s[2]), p3 = exp2f(s[3]);
            lp += (p0 + p1) + (p2 + p3);
            u32 lo = __builtin_amdgcn_perm(fbits(p1), fbits(p0), 0x07060302u);
            u32 hi = __builtin_amdgcn_perm(fbits(p3), fbits(p2), 0x07060302u);
            u32* dst = (u32*)(sP[wave] + l16 * 72 + t * 16 + quad * 4);
            dst[0] = lo; dst[1] = hi;
        }
        #pragma unroll
        for (int c = 0; c < 2; ++c) {
            bf16x8 pf = *(const bf16x8*)(sP[wave] + l16 * 72 + c * 32 + quad * 8);
            bf16x8 v0 = *(const bf16x8*)(sV + l16 * 72 + c * 32 + quad * 8);
            bf16x8 v1 = *(const bf16x8*)(sV + (16 + l16) * 72 + c * 32 + quad * 8);
            oacc0 = __builtin_amdgcn_mfma_f32_16x16x32_bf16(pf, v0, oacc0, 0, 0, 0);
            oacc1 = __builtin_amdgcn_mfma_f32_16x16x32_bf16(pf, v1, oacc1, 0, 0, 0);
        }
    }

    lp += __shfl_xor(lp, 16, 64);
    lp += __shfl_xor(lp, 32, 64);
    if (quad == 0)
        lpart_g[(long)(mh * 4 + ks) * NA + q0 + l16] = lp;

    #pragma unroll
    for (int r = 0; r < 4; ++r) {
        int qr = q0 + quad * 4 + r;
        long ob = ((long)(mh * 4 + ks) * NA + qr) * 32;
        opart[ob + l16]      = oacc0[r];
        opart[ob + 16 + l16] = oacc1[r];
    }
}

__global__ void attn_combine(const float* __restrict__ opart,
                             const float* __restrict__ lpart,
                             ushort* __restrict__ ctxb)
{
    int idx = blockIdx.x * 256 + threadIdx.x;   // 8*4096*32
    int d = idx & 31;
    int row = idx >> 5;
    int mh = row >> 12, qrow = row & 4095;
    float o = 0.f, l = 0.f;
    #pragma unroll
    for (int ks = 0; ks < 4; ++ks) {
        long rb = (long)(mh * 4 + ks) * NA + qrow;
        o += opart[rb * 32 + d];
        l += lpart[rb];
    }
    int m = mh >> 2, h = mh & 3;
    ctxb[((long)qrow * 2 + m) * 128 + h * 32 + d] = f2b(o / l);
}

// out[a][o] = sum_d 0.5*(x2[2a][d]+x2[2a+1][d]) * Wc[o][d] + bc[o]
__global__ void classify_kernel(const float* __restrict__ x2,
                                const float* __restrict__ Wc,
                                const float* __restrict__ bc,
                                float* __restrict__ out)
{
    int idx = blockIdx.x * 256 + threadIdx.x;
    int a2 = idx >> 4, o = idx & 15;
    const float* r0 = x2 + (long)(a2 * 2) * 128;
    const float* r1 = r0 + 128;
    const float* w = Wc + o * 128;
    float acc = bc[o];
    #pragma unroll 4
    for (int dd = 0; dd < 128; ++dd) acc += 0.5f * (r0[dd] + r1[dd]) * w[dd];
    out[idx] = acc;
}

// ---------------------------------------------------------------------------
static void bgemm(hipStream_t st, const ushort* Abf, const float* Af32, int lda,
                  const ushort* B, int ldb,
                  const float* bias, float* outf, ushort* outh, int ldc,
                  int M, int N, int K, int act = 0, int ksplit = 1)
{
    dim3 grid(N / 128, (M + 127) / 128, ksplit);
    gemm_bf16<<<grid, 256, 0, st>>>(Abf, Af32, lda, B, ldb, bias, outf, outh,
                                    ldc, M, N, K, act);
}

// streaming gemm launcher (N=128, K<=256)
static void sgemm(hipStream_t st, const ushort* Abf, const float* Af32, int lda,
                  const ushort* B, int ldb,
                  const float* bias, float* outf, ushort* outh, int ldc,
                  int M, int K, int act = 0)
{
    int nstripes = (M + 15) / 16;
    int grid = (nstripes + 3) / 4;
    if (grid > 2048) grid = 2048;
    size_t lds = (size_t)(K / 32) * 8 * 1024;
    gemm_stream<<<grid, 256, lds, st>>>(Abf, Af32, lda, B, ldb, bias,
                                        outf, outh, ldc, M, K, act);
}

static void build_csr(hipStream_t st, const int* src, const int* dst, int E, int n,
                      int* cnt, int* off, int* cur, int* bsum, int* esrc)
{
    hipMemsetAsync(cnt, 0, (size_t)n * 4, st);
    hist_kernel<<<(E + 255) / 256, 256, 0, st>>>(dst, cnt, E);
    int nb = (n + 1023) / 1024;
    scan_local<<<nb, 256, 0, st>>>(cnt, off, bsum, n);
    scan_local<<<1, 256, 0, st>>>(bsum, bsum, nullptr, nb);
    scan_add<<<(n + 255) / 256, 256, 0, st>>>(off, bsum, n);
    copy_int_kernel<<<(n + 255) / 256, 256, 0, st>>>(off, cur, n);
    fill_csr_kernel<<<(E + 255) / 256, 256, 0, st>>>(src, dst, cur, esrc, E);
}

extern "C" void kernel_launch(void* const* d_in, const int* in_sizes, int n_in,
                              void* d_out, int out_size, void* d_ws, size_t ws_size,
                              hipStream_t stream)
{
    const float* x_author = (const float*)d_in[0];
    const float* x_paper  = (const float*)d_in[1];
    const int*   src_ap   = (const int*)d_in[2];
    const int*   dst_ap   = (const int*)d_in[3];
    const int*   src_pa   = (const int*)d_in[4];
    const int*   dst_pa   = (const int*)d_in[5];
    const float* pa_W = (const float*)d_in[6];   const float* pa_b = (const float*)d_in[7];
    const float* pp_W = (const float*)d_in[8];   const float* pp_b = (const float*)d_in[9];
    const float* f_Wqkv = (const float*)d_in[10]; const float* f_bqkv = (const float*)d_in[11];
    const float* f_Wo = (const float*)d_in[12];  const float* f_bo = (const float*)d_in[13];
    const float* f_W1 = (const float*)d_in[14];  const float* f_b1 = (const float*)d_in[15];
    const float* f_W2 = (const float*)d_in[16];  const float* f_b2 = (const float*)d_in[17];
    const float* f_g1 = (const float*)d_in[18];  const float* f_bt1 = (const float*)d_in[19];
    const float* f_g2 = (const float*)d_in[20];  const float* f_bt2 = (const float*)d_in[21];
    const float* cls_W = (const float*)d_in[22]; const float* cls_b = (const float*)d_in[23];
    const float* l0_Wv = (const float*)d_in[24]; const float* l0_bv = (const float*)d_in[25];
    const float* l0_Wo = (const float*)d_in[26]; const float* l0_bo = (const float*)d_in[27];
    const float* l0_g  = (const float*)d_in[28]; const float* l0_b  = (const float*)d_in[29];
    const float* l1_Wv = (const float*)d_in[30]; const float* l1_bv = (const float*)d_in[31];
    const float* l1_Wo = (const float*)d_in[32]; const float* l1_bo = (const float*)d_in[33];
    const float* l1_g  = (const float*)d_in[34]; const float* l1_b  = (const float*)d_in[35];
    const float* l2_Wv = (const float*)d_in[36]; const float* l2_bv = (const float*)d_in[37];
    const float* l2_Wo = (const float*)d_in[38]; const float* l2_bo = (const float*)d_in[39];
    const float* l2_g  = (const float*)d_in[40]; const float* l2_b  = (const float*)d_in[41];

    // ---- workspace carve (bytes), overlays by liveness:
    uint8_t* w = (uint8_t*)d_ws;
    ushort* TB  = (ushort*)(w + 0);            // t bf16 [NP,128] 25.6MB
    ushort* FF  = (ushort*)(w + 26214400);     // ffn hidden bf16 [8192,2048] 33.6MB
    float*  OPART = (float*)(w + 26214400);    //   overlay (attn phase): 16MB
    float*  LPART = (float*)(w + 43515904);    //   + l partials 0.5MB
    ushort* HPB = (ushort*)(w + 61440000);     // [NP,128] bf16 25.6MB
    ushort* ZB  = (ushort*)(w + 87040000);     // z bf16 [NA,128] (step1 only)
    uint8_t* p2 = w + 102400000;               // phase-2 small tensors
    ushort* QKVB = (ushort*)(p2 + 0);          // [8192,384] bf16 6.29MB
    ushort* CTXB = (ushort*)(p2 + 6291456);    // [8192,128] bf16 2.1MB
    float*  TMP  = (float*)(p2 + 8388608);     // [8192,128] fp32 4.2MB
    float*  X1   = (float*)(p2 + 12582912);    // [8192,128] fp32
    ushort* X1B  = (ushort*)(p2 + 16777216);   // [8192,128] bf16
    float*  TMP2 = (float*)(p2 + 18874368);    // [8192,128] fp32
    float*  X2   = (float*)(p2 + 23068672);    // [8192,128] fp32
    uint8_t* tail = p2 + 27262976;             // persistent
    ushort* STKB  = (ushort*)(tail + 4194304); // [8192,128] bf16 (rows s*2+m)
    ushort* HAB   = (ushort*)(tail + 6291456); // [NA,128] bf16 1.05MB
    ushort* GMA   = (ushort*)(tail + 7340032); // gathered mean bf16 [NA,128]
    ushort* WFB   = (ushort*)(tail + 8388608); // 3x[128,128] bf16 98KB
    ushort* PAWB  = (ushort*)(tail + 8486912); // [128,128]
    ushort* PPWB  = (ushort*)(tail + 8519680); // [128,256]
    ushort* WQKVB = (ushort*)(tail + 8585216); // [384,128]
    ushort* WOB   = (ushort*)(tail + 8683520); // [128,128]
    ushort* W1B   = (ushort*)(tail + 8716288); // [2048,128]
    ushort* W2B   = (ushort*)(tail + 9240576); // [128,2048]
    float*  BEFF  = (float*)(tail + 9764864);  // 3x[128] fp32
    int*   CNT_A  = (int*)(tail + 9766400);
    int*   OFF_A  = (int*)(tail + 9782784);
    int*   CUR_A  = (int*)(tail + 9799168);
    int*   CNT_P  = (int*)(tail + 9815552);
    int*   OFF_P  = (int*)(tail + 10215552);
    int*   CUR_P  = (int*)(tail + 10615552);
    int*   ESRC_PA= (int*)(tail + 11015552);
    int*   ESRC_AP= (int*)(tail + 13015552);
    int*   BSUM_A = (int*)(tail + 15015552);
    int*   BSUM_P = (int*)(tail + 15016576);
    float* TMPA   = (float*)(tail + 15017984); // [NA,128] fp32 2.1MB

    // ---- convert weights to bf16 (activations convert in-GEMM)
    CvtArgs ca;
    ca.in[0] = pa_W;   ca.out[0] = PAWB;  ca.n4[0] = D * IN_A / 4;
    ca.in[1] = pp_W;   ca.out[1] = PPWB;  ca.n4[1] = D * IN_P / 4;
    ca.in[2] = f_Wqkv; ca.out[2] = WQKVB; ca.n4[2] = 3 * D * D / 4;
    ca.in[3] = f_Wo;   ca.out[3] = WOB;   ca.n4[3] = D * D / 4;
    ca.in[4] = f_W1;   ca.out[4] = W1B;   ca.n4[4] = DFF * D / 4;
    ca.in[5] = f_W2;   ca.out[5] = W2B;   ca.n4[5] = D * DFF / 4;
    cvt_multi<<<dim3((DFF * D / 4 + 255) / 256, 6), 256, 0, stream>>>(ca);

    fuse_weights<<<195, 256, 0, stream>>>(l0_Wv, l0_bv, l0_Wo, l0_bo,
                                          l1_Wv, l1_bv, l1_Wo, l1_bo,
                                          l2_Wv, l2_bv, l2_Wo, l2_bo, WFB, BEFF);

    // ---- CSR builds (pa reused by metapath 0 and metapath 1 step 2)
    build_csr(stream, src_pa, dst_pa, E_PA, NA, CNT_A, OFF_A, CUR_A, BSUM_A, ESRC_PA);
    build_csr(stream, src_ap, dst_ap, E_AP, NP, CNT_P, OFF_P, CUR_P, BSUM_P, ESRC_AP);

    // ---- node projections (streaming resident-B GEMM)
    sgemm(stream, nullptr, x_author, IN_A, PAWB, IN_A, pa_b, nullptr, HAB, D, NA, IN_A);
    sgemm(stream, nullptr, x_paper,  IN_P, PPWB, IN_P, pp_b, nullptr, HPB, D, NP, IN_P);

    // ---- metapath 0 (gather-first: mean commutes with linear projection)
    gather_mean<<<(NA + 7) / 8, 256, 0, stream>>>(HPB, OFF_A, CNT_A, ESRC_PA, GMA, NA);
    sgemm(stream, GMA, nullptr, D, WFB, D, nullptr, TMPA, nullptr, D, NA, D);
    mean_add_ln<<<NA, 128, 0, stream>>>(TMPA, BEFF, nullptr, HAB, l0_g, l0_b,
                                        nullptr, STKB, 256, NA);

    // ---- metapath 1 step 1: project (NA rows), gather into papers
    sgemm(stream, HAB, nullptr, D, WFB + 16384, D, BEFF + 128, nullptr, ZB, D, NA, D);
    gather_mean_ln<<<(NP + 7) / 8, 256, 0, stream>>>(
        ZB, OFF_P, CNT_P, ESRC_AP, HPB, l1_g, l1_b, TB, NP);

    // ---- metapath 1 step 2 (gather-first again)
    gather_mean<<<(NA + 7) / 8, 256, 0, stream>>>(TB, OFF_A, CNT_A, ESRC_PA, GMA, NA);
    sgemm(stream, GMA, nullptr, D, WFB + 32768, D, nullptr, TMPA, nullptr, D, NA, D);
    mean_add_ln<<<NA, 128, 0, stream>>>(TMPA, BEFF + 256, nullptr, HAB, l2_g, l2_b,
                                        nullptr, STKB + 128, 256, NA);

    // ---- fusion transformer: QKV as 3 N=128 streaming slices
    for (int n0 = 0; n0 < 3; ++n0)
        sgemm(stream, STKB, nullptr, D, WQKVB + n0 * 128 * D, D, f_bqkv + n0 * 128,
              nullptr, QKVB + n0 * 128, 3 * D, 2 * NA, D);
    flash_attn<<<dim3(NA / 64, 8, 4), 256, 0, stream>>>(QKVB, OPART, LPART);
    attn_combine<<<8 * NA * 32 / 256, 256, 0, stream>>>(OPART, LPART, CTXB);

    // x1 = LN(stk + ctx@Wo^T + bo): streaming Wo, bias folded into LN
    sgemm(stream, CTXB, nullptr, D, WOB, D, nullptr, TMP, nullptr, D, 2 * NA, D);
    mean_add_ln<<<2 * NA, 128, 0, stream>>>(TMP, f_bo, nullptr, STKB, f_g1, f_bt1,
                                            X1, X1B, 128, 2 * NA);

    // FFN: ff = relu(x1@W1^T+b1); x2 = LN(x1 + ff@W2^T + b2) (split-K W2)
    bgemm(stream, X1B, nullptr, D, W1B, D, f_b1, nullptr, FF, DFF, 2 * NA, DFF, D, 1);
    hipMemsetAsync(TMP2, 0, (size_t)2 * NA * D * 4, stream);
    bgemm(stream, FF, nullptr, DFF, W2B, DFF, nullptr, TMP2, nullptr, D, 2 * NA, D, DFF, 0, 8);
    mean_add_ln<<<2 * NA, 128, 0, stream>>>(TMP2, f_b2, X1, nullptr, f_g2, f_bt2,
                                            X2, nullptr, 128, 2 * NA);

    // ---- mean over metapaths + classifier (fp32)
    classify_kernel<<<(NA * NOUT) / 256, 256, 0, stream>>>(X2, cls_W, cls_b, (float*)d_out);
}